// Round 15
// baseline (176.644 us; speedup 1.0000x reference)
//
#include <hip/hip_runtime.h>
#include <hip/hip_bf16.h>

typedef unsigned short u16;
typedef unsigned int u32;

#define B_ 4
#define C_ 256
#define N_ 4096

// scale * log2(e) = (1/16) * 1.4426950408889634
constexpr float C1 = 0.09016844005556021f;

typedef float f32x16 __attribute__((ext_vector_type(16)));
typedef short bf16x8 __attribute__((ext_vector_type(8)));
typedef u32 u32x4 __attribute__((ext_vector_type(4)));
typedef int i32x2 __attribute__((ext_vector_type(2)));

__device__ __forceinline__ u16 bf16r(float f) {
    union { float f; u32 u; } a; a.f = f;
    u32 u = a.u;
    u += 0x7fffu + ((u >> 16) & 1u);   // RNE
    return (u16)(u >> 16);
}

__device__ __forceinline__ float bf2f(u16 h) {
    union { u32 u; float f; } a; a.u = ((u32)h) << 16; return a.f;
}

__device__ __forceinline__ u32 pk2(float a, float b) {
    __hip_bfloat162 h = __float22bfloat162_rn(make_float2(a, b)); // x=low
    union { __hip_bfloat162 h; u32 u; } c; c.h = h;
    return c.u;
}

__device__ __forceinline__ u32 cvtpk(float lo, float hi) {
    u32 r;
    asm("v_cvt_pk_bf16_f32 %0, %1, %2" : "=v"(r) : "v"(lo), "v"(hi));
    return r;
}

// permlane32_swap: a' = {a.lo32, b.lo32}, b' = {a.hi32, b.hi32}
__device__ __forceinline__ void swap32(u32 &a, u32 &b) {
#if __has_builtin(__builtin_amdgcn_permlane32_swap)
    i32x2 r = __builtin_amdgcn_permlane32_swap((int)a, (int)b, false, false);
    a = (u32)r.x; b = (u32)r.y;
#else
    u32 as = __shfl_xor(a, 32), bs = __shfl_xor(b, 32);
    int hi = (threadIdx.x & 32) ? 1 : 0;
    u32 na = hi ? bs : a;
    u32 nb = hi ? b : as;
    a = na; b = nb;
#endif
}

__device__ __forceinline__ bf16x8 ld8(const u16* p) {
    return *reinterpret_cast<const bf16x8*>(p);
}

// async global->LDS, 16B per lane; lbase must be wave-uniform (HW adds lane*16)
__device__ __forceinline__ void gld_lds16(const u16* g, u16* lbase, int lane) {
#if __has_builtin(__builtin_amdgcn_global_load_lds)
    __builtin_amdgcn_global_load_lds(
        (const __attribute__((address_space(1))) void*)g,
        (__attribute__((address_space(3))) void*)lbase, 16, 0, 0);
#else
    *reinterpret_cast<bf16x8*>(lbase + lane * 8) = ld8(g);
#endif
}

__device__ __forceinline__ int crow(int r, int hi) { return (r & 3) + 8 * (r >> 2) + 4 * hi; }

// ---------------- prep: weight casts + BN fold ----------------
__global__ __launch_bounds__(256) void prep(
    const float* __restrict__ Wq, const float* __restrict__ Wk,
    const float* __restrict__ Wv, const float* __restrict__ Wo,
    const float* __restrict__ bo, const float* __restrict__ gamma,
    const float* __restrict__ beta, const float* __restrict__ rm, const float* __restrict__ rv,
    u16* __restrict__ wqk, u16* __restrict__ wv_b, u16* __restrict__ wo_b,
    float* __restrict__ scale, float* __restrict__ shift)
{
    int i = blockIdx.x * 256 + threadIdx.x;
    if (i < 16384) {
        float w = (i < 8192) ? Wq[i] * C1 : Wk[i - 8192];
        wqk[i] = bf16r(w);
    } else if (i < 81920) {
        wv_b[i - 16384] = bf16r(Wv[i - 16384]);
    } else if (i < 147456) {
        wo_b[i - 81920] = bf16r(Wo[i - 81920]);
    } else if (i < 147712) {
        int o = i - 147456;
        float inv = gamma[o] * rsqrtf(rv[o] + 1e-5f);
        scale[o] = inv;
        shift[o] = beta[o] + (bo[o] - rm[o]) * inv;
    }
}

// ---------------- projf: fused transpose + q/k/v projections (64-n tiles) ----------------
__global__ __launch_bounds__(512) void projf(
    const float* __restrict__ x, const u16* __restrict__ wqk, const u16* __restrict__ wv,
    const float* __restrict__ bq, const float* __restrict__ bk, const float* __restrict__ bv,
    u16* __restrict__ qkt, u16* __restrict__ vout)
{
    __shared__ u16 xt[64 * 256];   // 32 KB
    int tid = threadIdx.x;
    int lane = tid & 63, wid = tid >> 6;
    int r31 = lane & 31, hi = lane >> 5;
    int b = blockIdx.y, n0 = blockIdx.x * 64;
    const float* xb = x + (size_t)b * C_ * N_ + n0;
#pragma unroll
    for (int i = 0; i < 16; ++i) {
        int c2 = i * 8 + wid;            // u32 column (channel pair), 0..127
        int n = lane;
        float a0 = xb[(size_t)(2 * c2) * N_ + n];
        float a1 = xb[(size_t)(2 * c2 + 1) * N_ + n];
        int slot = (c2 >> 2) ^ (n & 31);
        *reinterpret_cast<u32*>(&xt[n * 256 + slot * 8 + (c2 & 3) * 2]) = pk2(a0, a1);
    }
    __syncthreads();
    for (int i = 0; i < 3; ++i) {
        int t = wid + i * 8;
        if (t < 20) {
            bool isqk = (t < 4);
            int nb = isqk ? (t >> 1) * 32 : ((t - 4) & 1) * 32;
            int gb = isqk ? (t & 1) * 32 : ((t - 4) >> 1) * 32;  // o-base (qk) / c-base (v)
            const u16* grow = (isqk ? wqk : wv) + (size_t)(gb + r31) * C_ + hi * 8;
            f32x16 acc;
#pragma unroll
            for (int r = 0; r < 16; ++r) acc[r] = 0.f;
#pragma unroll
            for (int ks = 0; ks < 16; ++ks) {
                int slot = (2 * ks + hi) ^ r31;
                bf16x8 lf = ld8(&xt[(nb + r31) * 256 + slot * 8]);
                bf16x8 gf = ld8(grow + ks * 16);
                if (isqk) acc = __builtin_amdgcn_mfma_f32_32x32x16_bf16(lf, gf, acc, 0, 0, 0);
                else      acc = __builtin_amdgcn_mfma_f32_32x32x16_bf16(gf, lf, acc, 0, 0, 0);
            }
            if (isqk) {
                int o = gb + r31;
                float bias = (o < 32) ? bq[o] * C1 : bk[o - 32];
                u16* qrow = qkt + ((size_t)b * N_ + n0 + nb) * 64 + o;
#pragma unroll
                for (int r = 0; r < 16; ++r)
                    qrow[(size_t)crow(r, hi) * 64] = bf16r(acc[r] + bias);
            } else {
                u16* vb = vout + (size_t)b * C_ * N_ + n0 + nb + r31;
#pragma unroll
                for (int r = 0; r < 16; ++r) {
                    int c = gb + crow(r, hi);
                    vb[(size_t)c * N_] = bf16r(acc[r] + bv[c]);
                }
            }
        }
    }
}

// ---------------- attn: 4-warp block, warp = 32q x 256c, cross-ktile pipeline ----------------
// V LDS: 2 bufs [128 rows][16 slots][8e]  row=c>>1, slot sorig=(c&1)*8+(k>>3), at sorig^(row&15)
// K LDS: 3 bufs [16 rows][16 slots][8e]   row=k>>2, slot sorig=(k&3)*4+(d>>3), at sorig^row
// Pipeline: softmax(t+1) (VALU) overlaps PV(t) (MFMA): pfA/pfB double-state,
// K staged 2 tiles ahead (triple buffer), V 1 ahead (double buffer).
__global__ __launch_bounds__(256, 2) void attn(
    const u16* __restrict__ qkt, const u16* __restrict__ v,
    u16* __restrict__ opart, float* __restrict__ lpart, int kts)
{
    __shared__ char smem[77824];            // vt 2x32KB | ktt 3x4KB
    u16* vt0 = (u16*)smem;                  // V buf vs: vt0 + vs*16384 (u16)
    u16* kt0 = (u16*)(smem + 65536);        // K buf ks: kt0 + ks*2048 (u16)
    int tid = threadIdx.x;
    int lane = tid & 63, wid = tid >> 6;
    int r31 = lane & 31, hi = lane >> 5;

    // XCD-aware bijective swizzle of the flat workgroup id (nwg % 8 == 0)
    int nwg = 32 * 4 * gridDim.z;
    int wgl = blockIdx.x + 32 * (blockIdx.y + 4 * blockIdx.z);
    int cpx = nwg >> 3;
    int swzid = (wgl & 7) * cpx + (wgl >> 3);
    int bx = swzid & 31;
    int by = (swzid >> 5) & 3;
    int bz = swzid >> 7;

    int b = by, zs = bz;
    int q0 = bx * 128 + wid * 32;   // this warp's 32 query rows (all 256 channels)
    const u16* qkb = qkt + (size_t)b * N_ * 64;
    const u16* vbase = v + (size_t)b * C_ * N_;

    // K staging source (256 threads, 1 chunk each)
    int ks_row = tid >> 4;
    int ks_so = (tid & 15) ^ ks_row;
    int ks_k = ks_row * 4 + (ks_so >> 2);
    int ks_d8 = (ks_so & 3) * 8;

    // read-side precompute
    int cpar8 = (r31 & 1) * 8;     // (c&1)*8 (ct-invariant)
    int vrow0 = r31 >> 1;          // row2 for ct=0 (+16 per ct); also the XOR mask
    int kr4 = r31 >> 2;
    int kk3 = (r31 & 3) * 4;

    bf16x8 qf0 = ld8(qkb + (size_t)(q0 + r31) * 64 + hi * 8);
    bf16x8 qf1 = ld8(qkb + (size_t)(q0 + r31) * 64 + 16 + hi * 8);

    f32x16 acc[8];
#pragma unroll
    for (int ct = 0; ct < 8; ++ct)
#pragma unroll
        for (int r = 0; r < 16; ++r) acc[ct][r] = 0.f;

    f32x16 z4;
#pragma unroll
    for (int r = 0; r < 16; ++r) z4[r] = 0.f;

    float l0 = 0.f, l1 = 0.f, l2 = 0.f, l3 = 0.f;   // tree partials for l_run
    int ktBeg = zs * kts, ktEnd = (zs + 1) * kts;

    auto stageV = [&](int vs, int kt) {
        int k0 = kt * 64;
#pragma unroll
        for (int i = 0; i < 8; ++i) {
            int q = i * 256 + tid;
            int row2 = q >> 4;
            int so = (q & 15) ^ (row2 & 15);
            int c = 2 * row2 + (so >> 3);
            int kcol = (so & 7) * 8;
            gld_lds16(vbase + (size_t)c * N_ + k0 + kcol,
                      vt0 + vs * 16384 + (i * 256 + wid * 64) * 8, lane);
        }
    };
    auto stageK = [&](int ks, int kt) {
        int k0 = kt * 64;
        gld_lds16(qkb + (size_t)(k0 + ks_k) * 64 + 32 + ks_d8,
                  kt0 + ks * 2048 + wid * 512, lane);
    };

    // softmax for one 64-key tile (K slot kslot) -> 4 PV B-fragments + l partials
    auto qksm = [&](int kslot, bf16x8* pf) {
#pragma unroll
        for (int ph = 0; ph < 2; ++ph) {
            int krow = ph * 8 + kr4;
            const u16* kbase = kt0 + kslot * 2048 + krow * 128;
            bf16x8 kf0 = ld8(kbase + (((kk3 + hi) ^ krow) * 8));
            bf16x8 kf1 = ld8(kbase + (((kk3 + 2 + hi) ^ krow) * 8));
            f32x16 s = __builtin_amdgcn_mfma_f32_32x32x16_bf16(kf0, qf0, z4, 0, 0, 0);
            s = __builtin_amdgcn_mfma_f32_32x32x16_bf16(kf1, qf1, s, 0, 0, 0);
            float p[16];
#pragma unroll
            for (int r = 0; r < 16; ++r) p[r] = __builtin_amdgcn_exp2f(s[r]);
            l0 += (p[0] + p[1]) + (p[2] + p[3]);
            l1 += (p[4] + p[5]) + (p[6] + p[7]);
            l2 += (p[8] + p[9]) + (p[10] + p[11]);
            l3 += (p[12] + p[13]) + (p[14] + p[15]);
#pragma unroll
            for (int c16 = 0; c16 < 2; ++c16) {
                u32 w0 = cvtpk(p[8 * c16 + 0], p[8 * c16 + 1]);
                u32 w1 = cvtpk(p[8 * c16 + 2], p[8 * c16 + 3]);
                u32 w2 = cvtpk(p[8 * c16 + 4], p[8 * c16 + 5]);
                u32 w3 = cvtpk(p[8 * c16 + 6], p[8 * c16 + 7]);
                swap32(w0, w2);
                swap32(w1, w3);
                union { bf16x8 f8; u32 u[4]; } fu;
                fu.u[0] = w0; fu.u[1] = w1; fu.u[2] = w2; fu.u[3] = w3;
                pf[ph * 2 + c16] = fu.f8;
            }
        }
    };
    auto pv = [&](int vs, const bf16x8* pf) {
        __builtin_amdgcn_s_setprio(1);
#pragma unroll
        for (int ct = 0; ct < 8; ++ct) {
            const u16* vb2 = vt0 + vs * 16384 + (vrow0 + 16 * ct) * 128;
#pragma unroll
            for (int c = 0; c < 4; ++c) {
                bf16x8 vf = ld8(vb2 + (((cpar8 + 2 * c + hi) ^ vrow0) * 8));
                acc[ct] = __builtin_amdgcn_mfma_f32_32x32x16_bf16(vf, pf[c], acc[ct], 0, 0, 0);
            }
        }
        __builtin_amdgcn_s_setprio(0);
    };

    bf16x8 pfA[4], pfB[4];
    int vcur = 0;
    // prologue: V(t0), K(t0), K(t0+1); softmax(t0) -> pfA
    stageV(0, ktBeg);
    stageK(ktBeg % 3, ktBeg);
    if (ktBeg + 1 < ktEnd) stageK((ktBeg + 1) % 3, ktBeg + 1);
    __syncthreads();
    qksm(ktBeg % 3, pfA);

    for (int t = ktBeg; t < ktEnd; t += 2) {
        // even step: PV(t) with pfA; softmax(t+1) -> pfB overlaps
        if (t + 1 < ktEnd) stageV(vcur ^ 1, t + 1);
        if (t + 2 < ktEnd) stageK((t + 2) % 3, t + 2);
        if (t + 1 < ktEnd) qksm((t + 1) % 3, pfB);
        pv(vcur, pfA);
        __syncthreads();
        vcur ^= 1;
        if (t + 1 >= ktEnd) break;
        // odd step: PV(t+1) with pfB; softmax(t+2) -> pfA overlaps
        if (t + 2 < ktEnd) stageV(vcur ^ 1, t + 2);
        if (t + 3 < ktEnd) stageK((t + 3) % 3, t + 3);
        if (t + 2 < ktEnd) qksm((t + 2) % 3, pfA);
        pv(vcur, pfB);
        __syncthreads();
        vcur ^= 1;
    }

    // merge partials + partner hi-half once (deferred out of the k-loop)
    float l_run = (l0 + l1) + (l2 + l3);
    l_run += __shfl_xor(l_run, 32);

    // ---- epilogue: per-warp full-row transpose, no barriers, 1KB stores ----
    u16* dst = opart + ((size_t)(zs * B_ + b) * N_) * C_;
    if (hi == 0)
        lpart[((size_t)zs * B_ + b) * N_ + q0 + r31] = l_run;
    // warp-private slice: 32 rows x 528 B (512 data + 16 pad; 16B-aligned rows)
    char* ep = smem + wid * 16896;
#pragma unroll
    for (int ct = 0; ct < 8; ++ct)
#pragma unroll
        for (int rp = 0; rp < 8; ++rp) {
            int r2 = 2 * rp;
            int c = (r2 & 3) + 8 * (r2 >> 2) + 4 * hi;   // crow(r2,hi); even
            int cpos = ct * 16 + (c >> 1);               // u32-word position in row
            *reinterpret_cast<u32*>(ep + r31 * 528 + cpos * 4) =
                cvtpk(acc[ct][r2], acc[ct][r2 + 1]);
        }
    asm volatile("s_waitcnt lgkmcnt(0)" ::: "memory");
    __builtin_amdgcn_sched_barrier(0);
#pragma unroll
    for (int i = 0; i < 16; ++i) {
        int row = 2 * i + (lane >> 5);
        u32x4 w = *reinterpret_cast<const u32x4*>(ep + row * 528 + (lane & 31) * 16);
        *reinterpret_cast<u32x4*>(dst + (size_t)(q0 + row) * C_ + (lane & 31) * 8) = w;
    }
}

// ---------------- outprojf: merge partials + Wo GEMM + BN + residual + relu (64-n) ----------------
__global__ __launch_bounds__(512) void outprojf(
    const u16* __restrict__ opart, const float* __restrict__ lpart,
    const u16* __restrict__ wo, const float* __restrict__ scl, const float* __restrict__ shf,
    const float* __restrict__ x, float* __restrict__ out, int S)
{
    __shared__ u16 ot[64 * 256];   // 32 KB
    __shared__ float linv[64];
    int tid = threadIdx.x;
    int lane = tid & 63, wid = tid >> 6;
    int r31 = lane & 31, hi = lane >> 5;
    int b = blockIdx.y, n0 = blockIdx.x * 64;
    if (tid < 64) {
        float l = 0.f;
        for (int s = 0; s < S; ++s) l += lpart[((size_t)s * B_ + b) * N_ + n0 + tid];
        linv[tid] = 1.f / l;
    }
    __syncthreads();
#pragma unroll
    for (int i = 0; i < 4; ++i) {
        int chunk = i * 512 + tid;          // 2048 chunks of 8 channels
        int n = chunk >> 5, c8 = chunk & 31;
        float a[8];
#pragma unroll
        for (int j = 0; j < 8; ++j) a[j] = 0.f;
        for (int s = 0; s < S; ++s) {
            bf16x8 o = ld8(opart + (((size_t)s * B_ + b) * N_ + n0 + n) * C_ + c8 * 8);
#pragma unroll
            for (int j = 0; j < 8; ++j) a[j] += bf2f((u16)o[j]);
        }
        float li = linv[n];
        u32x4 w;
#pragma unroll
        for (int j = 0; j < 4; ++j) w[j] = pk2(a[2 * j] * li, a[2 * j + 1] * li);
        int sws = c8 ^ (n & 31);
        *reinterpret_cast<u32x4*>(&ot[n * 256 + sws * 8]) = w;
    }
    __syncthreads();
    // GEMM: warp strip 32 o x 64 n
    int obs = wid * 32;
    const u16* arow = wo + (size_t)(obs + r31) * C_ + hi * 8;
    f32x16 acc0, acc1;
#pragma unroll
    for (int r = 0; r < 16; ++r) { acc0[r] = 0.f; acc1[r] = 0.f; }
#pragma unroll
    for (int ks = 0; ks < 16; ++ks) {
        bf16x8 af = ld8(arow + ks * 16);
        int slot = (2 * ks + hi) ^ r31;
        bf16x8 b0 = ld8(&ot[r31 * 256 + slot * 8]);
        bf16x8 b1 = ld8(&ot[(32 + r31) * 256 + slot * 8]);
        acc0 = __builtin_amdgcn_mfma_f32_32x32x16_bf16(af, b0, acc0, 0, 0, 0);
        acc1 = __builtin_amdgcn_mfma_f32_32x32x16_bf16(af, b1, acc1, 0, 0, 0);
    }
    const float* xb = x + (size_t)b * C_ * N_;
    float* op = out + (size_t)b * C_ * N_;
#pragma unroll
    for (int r = 0; r < 16; ++r) {
        int o = obs + crow(r, hi);
        float sc = scl[o], sh = shf[o];
        size_t base = (size_t)o * N_ + n0;
        float v0 = acc0[r] * sc + sh + xb[base + r31];
        op[base + r31] = fmaxf(v0, 0.f);
        float v1 = acc1[r] * sc + sh + xb[base + 32 + r31];
        op[base + 32 + r31] = fmaxf(v1, 0.f);
    }
}

extern "C" void kernel_launch(void* const* d_in, const int* in_sizes, int n_in,
                              void* d_out, int out_size, void* d_ws, size_t ws_size,
                              hipStream_t stream) {
    const float* x     = (const float*)d_in[0];
    const float* Wq    = (const float*)d_in[1];
    const float* bq    = (const float*)d_in[2];
    const float* Wk    = (const float*)d_in[3];
    const float* bk    = (const float*)d_in[4];
    const float* Wv    = (const float*)d_in[5];
    const float* bv    = (const float*)d_in[6];
    const float* Wo    = (const float*)d_in[7];
    const float* bo    = (const float*)d_in[8];
    const float* gamma = (const float*)d_in[9];
    const float* beta  = (const float*)d_in[10];
    const float* rmean = (const float*)d_in[11];
    const float* rvar  = (const float*)d_in[12];
    float* out = (float*)d_out;

    char* ws = (char*)d_ws;
    u16* vbuf = (u16*)(ws);                            // [B][C][N] bf16, 8 MB
    u16* qkt  = (u16*)(ws + (size_t)(8u << 20));       // [B][N][64] bf16, 2 MB
    char* wsm = ws + (size_t)(10u << 20);
    u16* wqk  = (u16*)(wsm);                  // 64x256
    u16* wv_b = (u16*)(wsm + 32768);          // 256x256
    u16* wo_b = (u16*)(wsm + 32768 + 131072); // 256x256
    float* scl = (float*)(wsm + 32768 + 262144);
    float* shf = scl + 256;
    float* lpart = (float*)(ws + (size_t)(11u << 20)); // [S][B][N] f32, <=256 KB
    u16* opart = (u16*)(ws + (size_t)(12u << 20));     // [S][B][N][C] bf16, S*8 MB

    size_t need4 = (size_t)(12u << 20) + 4 * (size_t)(8u << 20);
    size_t need2 = (size_t)(12u << 20) + 2 * (size_t)(8u << 20);
    int S = (ws_size >= need4) ? 4 : (ws_size >= need2) ? 2 : 1;

    prep<<<dim3(578), dim3(256), 0, stream>>>(Wq, Wk, Wv, Wo, bo, gamma, beta, rmean, rvar,
                                              wqk, wv_b, wo_b, scl, shf);
    projf<<<dim3(64, 4), dim3(512), 0, stream>>>(x, wqk, wv_b, bq, bk, bv, qkt, vbuf);
    attn<<<dim3(32, 4, S), dim3(256), 0, stream>>>(qkt, vbuf, opart, lpart, 64 / S);
    outprojf<<<dim3(64, 4), dim3(512), 0, stream>>>(opart, lpart, wo_b, scl, shf, x, out, S);
}

// Round 16
// 79.709 us; speedup vs baseline: 2.2161x; 2.2161x over previous
//
#include <hip/hip_runtime.h>
#include <hip/hip_bf16.h>

typedef unsigned short u16;
typedef unsigned int u32;

#define B_ 4
#define C_ 256
#define N_ 4096

// scale * log2(e) = (1/16) * 1.4426950408889634
constexpr float C1 = 0.09016844005556021f;

typedef float f32x16 __attribute__((ext_vector_type(16)));
typedef short bf16x8 __attribute__((ext_vector_type(8)));
typedef u32 u32x4 __attribute__((ext_vector_type(4)));
typedef int i32x2 __attribute__((ext_vector_type(2)));

__device__ __forceinline__ u16 bf16r(float f) {
    union { float f; u32 u; } a; a.f = f;
    u32 u = a.u;
    u += 0x7fffu + ((u >> 16) & 1u);   // RNE
    return (u16)(u >> 16);
}

__device__ __forceinline__ float bf2f(u16 h) {
    union { u32 u; float f; } a; a.u = ((u32)h) << 16; return a.f;
}

__device__ __forceinline__ u32 pk2(float a, float b) {
    __hip_bfloat162 h = __float22bfloat162_rn(make_float2(a, b)); // x=low
    union { __hip_bfloat162 h; u32 u; } c; c.h = h;
    return c.u;
}

__device__ __forceinline__ u32 cvtpk(float lo, float hi) {
    u32 r;
    asm("v_cvt_pk_bf16_f32 %0, %1, %2" : "=v"(r) : "v"(lo), "v"(hi));
    return r;
}

// permlane32_swap: a' = {a.lo32, b.lo32}, b' = {a.hi32, b.hi32}
__device__ __forceinline__ void swap32(u32 &a, u32 &b) {
#if __has_builtin(__builtin_amdgcn_permlane32_swap)
    i32x2 r = __builtin_amdgcn_permlane32_swap((int)a, (int)b, false, false);
    a = (u32)r.x; b = (u32)r.y;
#else
    u32 as = __shfl_xor(a, 32), bs = __shfl_xor(b, 32);
    int hi = (threadIdx.x & 32) ? 1 : 0;
    u32 na = hi ? bs : a;
    u32 nb = hi ? b : as;
    a = na; b = nb;
#endif
}

__device__ __forceinline__ bf16x8 ld8(const u16* p) {
    return *reinterpret_cast<const bf16x8*>(p);
}

// async global->LDS, 16B per lane; lbase must be wave-uniform (HW adds lane*16)
__device__ __forceinline__ void gld_lds16(const u16* g, u16* lbase, int lane) {
#if __has_builtin(__builtin_amdgcn_global_load_lds)
    __builtin_amdgcn_global_load_lds(
        (const __attribute__((address_space(1))) void*)g,
        (__attribute__((address_space(3))) void*)lbase, 16, 0, 0);
#else
    *reinterpret_cast<bf16x8*>(lbase + lane * 8) = ld8(g);
#endif
}

__device__ __forceinline__ int crow(int r, int hi) { return (r & 3) + 8 * (r >> 2) + 4 * hi; }

// ---------------- prep: weight casts + BN fold ----------------
__global__ __launch_bounds__(256) void prep(
    const float* __restrict__ Wq, const float* __restrict__ Wk,
    const float* __restrict__ Wv, const float* __restrict__ Wo,
    const float* __restrict__ bo, const float* __restrict__ gamma,
    const float* __restrict__ beta, const float* __restrict__ rm, const float* __restrict__ rv,
    u16* __restrict__ wqk, u16* __restrict__ wv_b, u16* __restrict__ wo_b,
    float* __restrict__ scale, float* __restrict__ shift)
{
    int i = blockIdx.x * 256 + threadIdx.x;
    if (i < 16384) {
        float w = (i < 8192) ? Wq[i] * C1 : Wk[i - 8192];
        wqk[i] = bf16r(w);
    } else if (i < 81920) {
        wv_b[i - 16384] = bf16r(Wv[i - 16384]);
    } else if (i < 147456) {
        wo_b[i - 81920] = bf16r(Wo[i - 81920]);
    } else if (i < 147712) {
        int o = i - 147456;
        float inv = gamma[o] * rsqrtf(rv[o] + 1e-5f);
        scale[o] = inv;
        shift[o] = beta[o] + (bo[o] - rm[o]) * inv;
    }
}

// ---------------- projf: fused transpose + q/k/v projections (64-n tiles) ----------------
__global__ __launch_bounds__(512) void projf(
    const float* __restrict__ x, const u16* __restrict__ wqk, const u16* __restrict__ wv,
    const float* __restrict__ bq, const float* __restrict__ bk, const float* __restrict__ bv,
    u16* __restrict__ qkt, u16* __restrict__ vout)
{
    __shared__ u16 xt[64 * 256];   // 32 KB
    int tid = threadIdx.x;
    int lane = tid & 63, wid = tid >> 6;
    int r31 = lane & 31, hi = lane >> 5;
    int b = blockIdx.y, n0 = blockIdx.x * 64;
    const float* xb = x + (size_t)b * C_ * N_ + n0;
#pragma unroll
    for (int i = 0; i < 16; ++i) {
        int c2 = i * 8 + wid;            // u32 column (channel pair), 0..127
        int n = lane;
        float a0 = xb[(size_t)(2 * c2) * N_ + n];
        float a1 = xb[(size_t)(2 * c2 + 1) * N_ + n];
        int slot = (c2 >> 2) ^ (n & 31);
        *reinterpret_cast<u32*>(&xt[n * 256 + slot * 8 + (c2 & 3) * 2]) = pk2(a0, a1);
    }
    __syncthreads();
    for (int i = 0; i < 3; ++i) {
        int t = wid + i * 8;
        if (t < 20) {
            bool isqk = (t < 4);
            int nb = isqk ? (t >> 1) * 32 : ((t - 4) & 1) * 32;
            int gb = isqk ? (t & 1) * 32 : ((t - 4) >> 1) * 32;  // o-base (qk) / c-base (v)
            const u16* grow = (isqk ? wqk : wv) + (size_t)(gb + r31) * C_ + hi * 8;
            f32x16 acc;
#pragma unroll
            for (int r = 0; r < 16; ++r) acc[r] = 0.f;
#pragma unroll
            for (int ks = 0; ks < 16; ++ks) {
                int slot = (2 * ks + hi) ^ r31;
                bf16x8 lf = ld8(&xt[(nb + r31) * 256 + slot * 8]);
                bf16x8 gf = ld8(grow + ks * 16);
                if (isqk) acc = __builtin_amdgcn_mfma_f32_32x32x16_bf16(lf, gf, acc, 0, 0, 0);
                else      acc = __builtin_amdgcn_mfma_f32_32x32x16_bf16(gf, lf, acc, 0, 0, 0);
            }
            if (isqk) {
                int o = gb + r31;
                float bias = (o < 32) ? bq[o] * C1 : bk[o - 32];
                u16* qrow = qkt + ((size_t)b * N_ + n0 + nb) * 64 + o;
#pragma unroll
                for (int r = 0; r < 16; ++r)
                    qrow[(size_t)crow(r, hi) * 64] = bf16r(acc[r] + bias);
            } else {
                u16* vb = vout + (size_t)b * C_ * N_ + n0 + nb + r31;
#pragma unroll
                for (int r = 0; r < 16; ++r) {
                    int c = gb + crow(r, hi);
                    vb[(size_t)c * N_] = bf16r(acc[r] + bv[c]);
                }
            }
        }
    }
}

// ---------------- attn: 4-warp block, warp = 32q x 256c, phase-merged pipeline ----------------
// V LDS: [128 rows][16 slots][8e]  row = c>>1, slot sorig=(c&1)*8+(k>>3), stored at sorig^(row&15)
// K LDS: [16 rows][16 slots][8e]   row = k>>2, slot sorig=(k&3)*4+(d>>3), stored at sorig^row
// Epilogue: per-warp full-row LDS transpose (no barriers), 1KB-coalesced stores.
__global__ __launch_bounds__(256, 2) void attn(
    const u16* __restrict__ qkt, const u16* __restrict__ v,
    u16* __restrict__ opart, float* __restrict__ lpart, int kts)
{
    __shared__ char smem[73728];            // manually partitioned: vt 2x32KB | ktt 2x4KB
    u16* vt0 = (u16*)smem;                  // vt[buf] = vt0 + buf*16384
    u16* kt0 = (u16*)(smem + 65536);        // ktt[buf] = kt0 + buf*2048
    int tid = threadIdx.x;
    int lane = tid & 63, wid = tid >> 6;
    int r31 = lane & 31, hi = lane >> 5;

    // XCD-aware bijective swizzle of the flat workgroup id (nwg % 8 == 0)
    int nwg = 32 * 4 * gridDim.z;
    int wgl = blockIdx.x + 32 * (blockIdx.y + 4 * blockIdx.z);
    int cpx = nwg >> 3;
    int swzid = (wgl & 7) * cpx + (wgl >> 3);
    int bx = swzid & 31;
    int by = (swzid >> 5) & 3;
    int bz = swzid >> 7;

    int b = by, zs = bz;
    int q0 = bx * 128 + wid * 32;   // this warp's 32 query rows (all 256 channels)
    const u16* qkb = qkt + (size_t)b * N_ * 64;
    const u16* vbase = v + (size_t)b * C_ * N_;

    // K staging source (256 threads, 1 chunk each)
    int ks_row = tid >> 4;
    int ks_so = (tid & 15) ^ ks_row;
    int ks_k = ks_row * 4 + (ks_so >> 2);
    int ks_d8 = (ks_so & 3) * 8;

    // read-side precompute
    int cpar8 = (r31 & 1) * 8;     // (c&1)*8 (ct-invariant)
    int vrow0 = r31 >> 1;          // row2 for ct=0 (+16 per ct); also the XOR mask
    int kr4 = r31 >> 2;
    int kk3 = (r31 & 3) * 4;

    bf16x8 qf0 = ld8(qkb + (size_t)(q0 + r31) * 64 + hi * 8);
    bf16x8 qf1 = ld8(qkb + (size_t)(q0 + r31) * 64 + 16 + hi * 8);

    f32x16 acc[8];
#pragma unroll
    for (int ct = 0; ct < 8; ++ct)
#pragma unroll
        for (int r = 0; r < 16; ++r) acc[ct][r] = 0.f;

    f32x16 z4;
#pragma unroll
    for (int r = 0; r < 16; ++r) z4[r] = 0.f;

    float l0 = 0.f, l1 = 0.f, l2 = 0.f, l3 = 0.f;   // tree partials for l_run
    int ktBeg = zs * kts, ktEnd = (zs + 1) * kts;

    auto stage = [&](int buf, int kt) {
        int k0 = kt * 64;
        gld_lds16(qkb + (size_t)(k0 + ks_k) * 64 + 32 + ks_d8,
                  kt0 + buf * 2048 + wid * 512, lane);
#pragma unroll
        for (int i = 0; i < 8; ++i) {
            int q = i * 256 + tid;
            int row2 = q >> 4;
            int so = (q & 15) ^ (row2 & 15);
            int c = 2 * row2 + (so >> 3);
            int kcol = (so & 7) * 8;
            gld_lds16(vbase + (size_t)c * N_ + k0 + kcol,
                      vt0 + buf * 16384 + (i * 256 + wid * 64) * 8, lane);
        }
    };

    int cur = 0;
    stage(cur, ktBeg);
    __syncthreads();   // drains prologue vmcnt

    for (int kt = ktBeg; kt < ktEnd; ++kt) {
        if (kt + 1 < ktEnd) stage(cur ^ 1, kt + 1);   // issue next tile's DMA first

        // ---- softmax section: both 32-key phases (independent chains) ----
        bf16x8 pfm[4];   // PV B-fragments for 16-key chunks 0..3
#pragma unroll
        for (int ph = 0; ph < 2; ++ph) {
            int krow = ph * 8 + kr4;
            const u16* kbase = kt0 + cur * 2048 + krow * 128;
            bf16x8 kf0 = ld8(kbase + (((kk3 + hi) ^ krow) * 8));
            bf16x8 kf1 = ld8(kbase + (((kk3 + 2 + hi) ^ krow) * 8));
            f32x16 s = __builtin_amdgcn_mfma_f32_32x32x16_bf16(kf0, qf0, z4, 0, 0, 0);
            s = __builtin_amdgcn_mfma_f32_32x32x16_bf16(kf1, qf1, s, 0, 0, 0);
            float p[16];
#pragma unroll
            for (int r = 0; r < 16; ++r) p[r] = __builtin_amdgcn_exp2f(s[r]);
            l0 += (p[0] + p[1]) + (p[2] + p[3]);
            l1 += (p[4] + p[5]) + (p[6] + p[7]);
            l2 += (p[8] + p[9]) + (p[10] + p[11]);
            l3 += (p[12] + p[13]) + (p[14] + p[15]);
            // repack P -> PV B-fragment via cvt_pk + permlane32_swap (T12)
#pragma unroll
            for (int c16 = 0; c16 < 2; ++c16) {
                u32 w0 = cvtpk(p[8 * c16 + 0], p[8 * c16 + 1]);
                u32 w1 = cvtpk(p[8 * c16 + 2], p[8 * c16 + 3]);
                u32 w2 = cvtpk(p[8 * c16 + 4], p[8 * c16 + 5]);
                u32 w3 = cvtpk(p[8 * c16 + 6], p[8 * c16 + 7]);
                swap32(w0, w2);
                swap32(w1, w3);
                union { bf16x8 f8; u32 u[4]; } fu;
                fu.u[0] = w0; fu.u[1] = w1; fu.u[2] = w2; fu.u[3] = w3;
                pfm[ph * 2 + c16] = fu.f8;
            }
        }

        // ---- PV section: one dense 32-MFMA cluster ----
        __builtin_amdgcn_s_setprio(1);
#pragma unroll
        for (int ct = 0; ct < 8; ++ct) {
            const u16* vb2 = vt0 + cur * 16384 + (vrow0 + 16 * ct) * 128;
#pragma unroll
            for (int c = 0; c < 4; ++c) {
                bf16x8 vf = ld8(vb2 + (((cpar8 + 2 * c + hi) ^ vrow0) * 8));
                acc[ct] = __builtin_amdgcn_mfma_f32_32x32x16_bf16(vf, pfm[c], acc[ct], 0, 0, 0);
            }
        }
        __builtin_amdgcn_s_setprio(0);

        __syncthreads();   // drains stage vmcnt (had full compute to land) + read-done
        cur ^= 1;
    }

    // merge partials + partner hi-half once (deferred out of the k-loop)
    float l_run = (l0 + l1) + (l2 + l3);
    l_run += __shfl_xor(l_run, 32);

    // ---- epilogue: per-warp full-row transpose, no barriers, 1KB stores ----
    u16* dst = opart + ((size_t)(zs * B_ + b) * N_) * C_;
    if (hi == 0)
        lpart[((size_t)zs * B_ + b) * N_ + q0 + r31] = l_run;
    // warp-private slice: 32 rows x 528 B (512 data + 16 pad; 16B-aligned rows)
    char* ep = smem + wid * 16896;
#pragma unroll
    for (int ct = 0; ct < 8; ++ct)
#pragma unroll
        for (int rp = 0; rp < 8; ++rp) {
            int r2 = 2 * rp;
            int c = (r2 & 3) + 8 * (r2 >> 2) + 4 * hi;   // crow(r2,hi); even
            int cpos = ct * 16 + (c >> 1);               // u32-word position in row
            *reinterpret_cast<u32*>(ep + r31 * 528 + cpos * 4) =
                cvtpk(acc[ct][r2], acc[ct][r2 + 1]);
        }
    asm volatile("s_waitcnt lgkmcnt(0)" ::: "memory");
    __builtin_amdgcn_sched_barrier(0);
#pragma unroll
    for (int i = 0; i < 16; ++i) {
        int row = 2 * i + (lane >> 5);
        u32x4 w = *reinterpret_cast<const u32x4*>(ep + row * 528 + (lane & 31) * 16);
        *reinterpret_cast<u32x4*>(dst + (size_t)(q0 + row) * C_ + (lane & 31) * 8) = w;
    }
}

// ---------------- outprojf: merge partials + Wo GEMM + BN + residual + relu (64-n) ----------------
__global__ __launch_bounds__(512) void outprojf(
    const u16* __restrict__ opart, const float* __restrict__ lpart,
    const u16* __restrict__ wo, const float* __restrict__ scl, const float* __restrict__ shf,
    const float* __restrict__ x, float* __restrict__ out, int S)
{
    __shared__ u16 ot[64 * 256];   // 32 KB
    __shared__ float linv[64];
    int tid = threadIdx.x;
    int lane = tid & 63, wid = tid >> 6;
    int r31 = lane & 31, hi = lane >> 5;
    int b = blockIdx.y, n0 = blockIdx.x * 64;
    if (tid < 64) {
        float l = 0.f;
        for (int s = 0; s < S; ++s) l += lpart[((size_t)s * B_ + b) * N_ + n0 + tid];
        linv[tid] = 1.f / l;
    }
    __syncthreads();
#pragma unroll
    for (int i = 0; i < 4; ++i) {
        int chunk = i * 512 + tid;          // 2048 chunks of 8 channels
        int n = chunk >> 5, c8 = chunk & 31;
        float a[8];
#pragma unroll
        for (int j = 0; j < 8; ++j) a[j] = 0.f;
        for (int s = 0; s < S; ++s) {
            bf16x8 o = ld8(opart + (((size_t)s * B_ + b) * N_ + n0 + n) * C_ + c8 * 8);
#pragma unroll
            for (int j = 0; j < 8; ++j) a[j] += bf2f((u16)o[j]);
        }
        float li = linv[n];
        u32x4 w;
#pragma unroll
        for (int j = 0; j < 4; ++j) w[j] = pk2(a[2 * j] * li, a[2 * j + 1] * li);
        int sws = c8 ^ (n & 31);
        *reinterpret_cast<u32x4*>(&ot[n * 256 + sws * 8]) = w;
    }
    __syncthreads();
    // GEMM: warp strip 32 o x 64 n
    int obs = wid * 32;
    const u16* arow = wo + (size_t)(obs + r31) * C_ + hi * 8;
    f32x16 acc0, acc1;
#pragma unroll
    for (int r = 0; r < 16; ++r) { acc0[r] = 0.f; acc1[r] = 0.f; }
#pragma unroll
    for (int ks = 0; ks < 16; ++ks) {
        bf16x8 af = ld8(arow + ks * 16);
        int slot = (2 * ks + hi) ^ r31;
        bf16x8 b0 = ld8(&ot[r31 * 256 + slot * 8]);
        bf16x8 b1 = ld8(&ot[(32 + r31) * 256 + slot * 8]);
        acc0 = __builtin_amdgcn_mfma_f32_32x32x16_bf16(af, b0, acc0, 0, 0, 0);
        acc1 = __builtin_amdgcn_mfma_f32_32x32x16_bf16(af, b1, acc1, 0, 0, 0);
    }
    const float* xb = x + (size_t)b * C_ * N_;
    float* op = out + (size_t)b * C_ * N_;
#pragma unroll
    for (int r = 0; r < 16; ++r) {
        int o = obs + crow(r, hi);
        float sc = scl[o], sh = shf[o];
        size_t base = (size_t)o * N_ + n0;
        float v0 = acc0[r] * sc + sh + xb[base + r31];
        op[base + r31] = fmaxf(v0, 0.f);
        float v1 = acc1[r] * sc + sh + xb[base + 32 + r31];
        op[base + 32 + r31] = fmaxf(v1, 0.f);
    }
}

extern "C" void kernel_launch(void* const* d_in, const int* in_sizes, int n_in,
                              void* d_out, int out_size, void* d_ws, size_t ws_size,
                              hipStream_t stream) {
    const float* x     = (const float*)d_in[0];
    const float* Wq    = (const float*)d_in[1];
    const float* bq    = (const float*)d_in[2];
    const float* Wk    = (const float*)d_in[3];
    const float* bk    = (const float*)d_in[4];
    const float* Wv    = (const float*)d_in[5];
    const float* bv    = (const float*)d_in[6];
    const float* Wo    = (const float*)d_in[7];
    const float* bo    = (const float*)d_in[8];
    const float* gamma = (const float*)d_in[9];
    const float* beta  = (const float*)d_in[10];
    const float* rmean = (const float*)d_in[11];
    const float* rvar  = (const float*)d_in[12];
    float* out = (float*)d_out;

    char* ws = (char*)d_ws;
    u16* vbuf = (u16*)(ws);                            // [B][C][N] bf16, 8 MB
    u16* qkt  = (u16*)(ws + (size_t)(8u << 20));       // [B][N][64] bf16, 2 MB
    char* wsm = ws + (size_t)(10u << 20);
    u16* wqk  = (u16*)(wsm);                  // 64x256
    u16* wv_b = (u16*)(wsm + 32768);          // 256x256
    u16* wo_b = (u16*)(wsm + 32768 + 131072); // 256x256
    float* scl = (float*)(wsm + 32768 + 262144);
    float* shf = scl + 256;
    float* lpart = (float*)(ws + (size_t)(11u << 20)); // [S][B][N] f32, <=256 KB
    u16* opart = (u16*)(ws + (size_t)(12u << 20));     // [S][B][N][C] bf16, S*8 MB

    size_t need4 = (size_t)(12u << 20) + 4 * (size_t)(8u << 20);
    size_t need2 = (size_t)(12u << 20) + 2 * (size_t)(8u << 20);
    int S = (ws_size >= need4) ? 4 : (ws_size >= need2) ? 2 : 1;

    prep<<<dim3(578), dim3(256), 0, stream>>>(Wq, Wk, Wv, Wo, bo, gamma, beta, rmean, rvar,
                                              wqk, wv_b, wo_b, scl, shf);
    projf<<<dim3(64, 4), dim3(512), 0, stream>>>(x, wqk, wv_b, bq, bk, bv, qkt, vbuf);
    attn<<<dim3(32, 4, S), dim3(256), 0, stream>>>(qkt, vbuf, opart, lpart, 64 / S);
    outprojf<<<dim3(64, 4), dim3(512), 0, stream>>>(opart, lpart, wo_b, scl, shf, x, out, S);
}